// Round 10
// baseline (1089.310 us; speedup 1.0000x reference)
//
#include <hip/hip_runtime.h>

typedef _Float16 f16;
typedef _Float16 f16x2 __attribute__((ext_vector_type(2)));
typedef _Float16 f16x4 __attribute__((ext_vector_type(4)));
typedef _Float16 f16x8 __attribute__((ext_vector_type(8)));
typedef float floatx4 __attribute__((ext_vector_type(4)));

// Problem constants (fixed by the reference)
constexpr int NC = 100000;   // cards
constexpr int NM = 20000;    // merchants
constexpr int NE = 400000;   // edges per edge-type

// d_out layout (floats), concat of (xc2, xm2, pred_c, pred_m, risk_c, risk_m)
constexpr int OFF_XM2 = NC * 128;
constexpr int OFF_PC  = OFF_XM2 + NM * 128;
constexpr int OFF_PM  = OFF_PC + NC * 2;
constexpr int OFF_RC  = OFF_PM + NM * 2;
constexpr int OFF_RM  = OFF_RC + NC;

__device__ __forceinline__ int bpermi(int v, int srclane) {
  return __builtin_amdgcn_ds_bpermute(srclane << 2, v);
}
__device__ __forceinline__ float bpermf(float v, int srclane) {
  int r = __builtin_amdgcn_ds_bpermute(srclane << 2, __builtin_bit_cast(int, v));
  return __builtin_bit_cast(float, r);
}
// DPP cross-lane permute (~4-8cy vs ~35cy for ds_bpermute).
// CTRL: 0x00-0xFF quad_perm; 0x120+N row_ror:N (rotate within 16-lane row).
// Rotations by multiples of 4 preserve head (lane&3) alignment and cover the
// full stride-4 congruence class after ror4+ror8 — equivalent to xor4/xor8
// for max/sum reductions.
template<int CTRL>
__device__ __forceinline__ float dppf(float v) {
  int r = __builtin_amdgcn_update_dpp(0, __builtin_bit_cast(int, v),
                                      CTRL, 0xf, 0xf, true);
  return __builtin_bit_cast(float, r);
}
constexpr int DPP_ROR4  = 0x124;
constexpr int DPP_ROR8  = 0x128;
constexpr int DPP_XOR1  = 0xB1;   // quad_perm [1,0,3,2]
constexpr int DPP_XOR2  = 0x4E;   // quad_perm [2,3,0,1]
// order-preserving float<->uint key (monotonic: a<b <=> fkey(a)<fkey(b));
// all fkey outputs > 0, so 0 is a safe atomicMax identity.
__device__ __forceinline__ unsigned fkey(float f) {
  unsigned u = __builtin_bit_cast(unsigned, f);
  return (u >> 31) ? ~u : (u | 0x80000000u);
}
__device__ __forceinline__ float fdec(unsigned k) {
  unsigned u = (k >> 31) ? (k ^ 0x80000000u) : ~k;
  return __builtin_bit_cast(float, u);
}

// stats layout (uint/float slots): [0..15] card max-keys, [16..31] merchant
// max-keys (atomicMax over fkey, 16 slots per type to spread contention),
// [32] den_card, [33] den_merchant.

// ---------------------------------------------------------------- fused prep + hist
// block 0: a_d GEMV vectors + bias concat + stats init.
// blocks 1..20: swizzle W matrices into MFMA B-fragment fp16 order.
// blocks 21..: edge histogram; the atomicAdd return value IS the edge's rank
// within its dst segment (captured -> scatter becomes atomic-free).
// Counter zeroing is done by hipMemsetAsync BEFORE this kernel (no intra-kernel
// cross-block ordering assumptions).
// B-frag layout (16x16x32): lane holds B[k=kt*32+(lane>>4)*8+j][n=ct*16+(lane&15)],
// flat: dst[((kt*8+ct)*64+lane)*8+j]
__global__ void __launch_bounds__(256) k_prep(
    int* stats_i,
    const float* W0, const float* a0, float* v0,
    const float* W1, const float* a1, float* v1,
    const float* W2, const float* a2, float* v2,
    const float* W3, const float* a3, float* v3,
    const float* cb1, const float* mb1, const float* rb1, float* bC, float* bM,
    const float* S0, const float* S1, const float* S2, const float* S3,
    const float* c1, const float* m1, const float* r1,
    f16* BfL0cm, f16* BfL0mc, f16* BfL1cm, f16* BfL1mc, f16* BfC, f16* BfM,
    const int* cm_dst, const int* mc_dst, int* cnt_cm, int* cnt_mc,
    int* rank_cm, int* rank_mc) {
  int b = blockIdx.x, t = threadIdx.x;
  if (b == 0) {
    const float* Wd[4] = {W0, W1, W2, W3};
    const float* ad[4] = {a0, a1, a2, a3};
    float* vd[4] = {v0, v1, v2, v3};
    for (int idx = t; idx < 1536; idx += 256) {
      int mat, base;
      if (idx < 256)       { mat = 0; base = 0; }
      else if (idx < 512)  { mat = 1; base = 256; }
      else if (idx < 1024) { mat = 2; base = 512; }
      else                 { mat = 3; base = 1024; }
      int local = idx - base, k = local >> 2, h = local & 3;
      const float* W = Wd[mat]; const float* a = ad[mat];
      float s = 0.f;
      for (int c = 0; c < 32; ++c) s += W[k * 128 + h * 32 + c] * a[h * 32 + c];
      vd[mat][local] = s;
    }
    if (t < 128) {
      bC[t] = (t < 64) ? cb1[t] : rb1[t - 64];
      bM[t] = (t < 64) ? mb1[t] : rb1[t - 64];
    }
    if (t < 34) stats_i[t] = 0;   // 32 max-key slots + 2 dens
  } else if (b <= 20) {
    int s = b - 1;
    const float* Wp = nullptr; const float* cA = nullptr; const float* cB = nullptr;
    f16* dst; int kt;
    if (s < 2)       { Wp = S0; dst = BfL0cm; kt = s; }
    else if (s < 4)  { Wp = S1; dst = BfL0mc; kt = s - 2; }
    else if (s < 8)  { Wp = S2; dst = BfL1cm; kt = s - 4; }
    else if (s < 12) { Wp = S3; dst = BfL1mc; kt = s - 8; }
    else if (s < 16) { cA = c1; cB = r1; dst = BfC; kt = s - 12; }
    else             { cA = m1; cB = r1; dst = BfM; kt = s - 16; }
    for (int e = t; e < 512; e += 256) {
      int lane = e & 63, ct = e >> 6;
      int m = lane & 15, q = lane >> 4;
      int col = ct * 16 + m;
      f16x8 frag;
      #pragma unroll
      for (int j = 0; j < 8; ++j) {
        int k = kt * 32 + q * 8 + j;
        float val = Wp ? Wp[k * 128 + col]
                       : (col < 64 ? cA[k * 64 + col] : cB[k * 64 + (col - 64)]);
        frag[j] = (f16)val;
      }
      *reinterpret_cast<f16x8*>(&dst[(size_t)((kt * 8 + ct) * 64 + lane) * 8]) = frag;
    }
  } else {
    int i = (b - 21) * 256 + t;
    if (i < NE) {
      rank_cm[i] = atomicAdd(&cnt_cm[cm_dst[i]], 1);
      rank_mc[i] = atomicAdd(&cnt_mc[mc_dst[i]], 1);
    }
  }
}

__global__ void __launch_bounds__(256) k_scan1(const int* cnt_cm, const int* cnt_mc,
                                               int* offs_cm, int* offs_mc, int* parts) {
  int b = blockIdx.x;
  const int* cnt; int* offs; int n, chunk;
  if (b < 20) { cnt = cnt_cm; offs = offs_cm; n = NM; chunk = b; }
  else        { cnt = cnt_mc; offs = offs_mc; n = NC; chunk = b - 20; }
  int t = threadIdx.x;
  int base = chunk * 1024;
  int v[4]; int tsum = 0;
  #pragma unroll
  for (int j = 0; j < 4; ++j) {
    int idx = base + t * 4 + j;
    v[j] = (idx < n) ? cnt[idx] : 0;
    tsum += v[j];
  }
  __shared__ int sd[256];
  sd[t] = tsum; __syncthreads();
  for (int off = 1; off < 256; off <<= 1) {
    int x = (t >= off) ? sd[t - off] : 0;
    __syncthreads();
    sd[t] += x;
    __syncthreads();
  }
  int excl = sd[t] - tsum;
  int r = excl;
  #pragma unroll
  for (int j = 0; j < 4; ++j) {
    int idx = base + t * 4 + j;
    if (idx < n) offs[idx] = r;
    r += v[j];
  }
  if (t == 0) parts[b] = sd[255];
}

// scan2 merged in: every block redundantly scans the 118 raw partials in LDS
// (parts stays raw -> no cross-block ordering hazard), then applies its slice.
__global__ void __launch_bounds__(256) k_scan3(int* offs_cm, int* offs_mc, const int* parts) {
  __shared__ int sd[128];
  int t = threadIdx.x;
  if (t < 128) sd[t] = (t < 118) ? parts[t] : 0;
  __syncthreads();
  for (int off = 1; off < 128; off <<= 1) {
    int x = 0;
    if (t < 128 && t >= off) x = sd[t - off];
    __syncthreads();
    if (t < 128) sd[t] += x;
    __syncthreads();
  }
  // sd[] now holds the inclusive scan of parts[0..117].
  // cm section = parts[0..19], mc section = parts[20..117]; exclusive within
  // each section: cm p -> sd[p-1]; mc p -> sd[19+p]-sd[19].
  int i = (int)blockIdx.x * 256 + t;
  if (i < NM) {
    int p = i >> 10;
    offs_cm[i] += p ? sd[p - 1] : 0;
  } else if (i < NM + NC) {
    int j = i - NM;
    int p = j >> 10;
    offs_mc[j] += p ? sd[19 + p] - sd[19] : 0;
  }
  if (i == 0) { offs_cm[NM] = NE; offs_mc[NC] = NE; }
}

// ---------------------------------------------------------------- MFMA GEMM
// 64-row x 128-col tile per 256-thread block; 4 waves, each: 16 rows x 128 cols
// via 8 col-tiles of mfma_f32_16x16x32_f16 over K/32 k-tiles.
// C/D layout: col = ct*16 + (lane&15), row = (lane>>4)*4 + reg
// K=64/EPI=0 instantiation additionally carries the atomic-free CSR scatter in
// extra grid blocks (blockIdx >= nGemm): the MFMA-bound gemm and the
// store-bound scatter use disjoint pipes and overlap in one dispatch.
struct GemmSide {
  const float* x; const f16* Bf;
  const float* asrc; const float* v; f16* hs; float* asO; float* adO;   // EPI 0
  const float* bias; const float* wnum; const float* den; float* outx;  // EPI 1
  const float* W2; const float* B2; const float* w2r; const float* b2r;
  float* pred; float* risk;
  int M;
};

struct ScatPack {
  const int* cm_src; const int* cm_dst; const int* mc_src; const int* mc_dst;
  const int* rank_cm; const int* rank_mc; const int* offs_cm; const int* offs_mc;
  int* csr_cm; int* csr_mc;
};

template<int K, int EPI>
__global__ void __launch_bounds__(256) k_gemm(GemmSide A, GemmSide B, int gridA,
                                              int nGemm, ScatPack sp) {
  if constexpr (K == 64 && EPI == 0) {
    if ((int)blockIdx.x >= nGemm) {
      int i = ((int)blockIdx.x - nGemm) * 256 + (int)threadIdx.x;
      if (i < NE) {
        int p = sp.offs_cm[sp.cm_dst[i]] + sp.rank_cm[i];
        sp.csr_cm[p] = sp.cm_src[i];
        int q = sp.offs_mc[sp.mc_dst[i]] + sp.rank_mc[i];
        sp.csr_mc[q] = sp.mc_src[i];
      }
      return;
    }
  }
  constexpr int PP = K + 8;        // fp16 pitch
  constexpr int F4 = K / 4;
  __shared__ f16 xs16[64 * PP];
  const bool isA = (int)blockIdx.x < gridA;
  GemmSide S = isA ? A : B;
  const int blk = isA ? (int)blockIdx.x : (int)blockIdx.x - gridA;
  const int rows0 = blk * 64;
  const int t = (int)threadIdx.x;
  float invden_s = 0.f;
  if constexpr (EPI == 1) invden_s = 1.0f / S.den[0];
  const float4* x4 = reinterpret_cast<const float4*>(S.x);
  #pragma unroll
  for (int ii = 0; ii < (64 * F4) / 256; ++ii) {
    int idx = t + ii * 256;
    int r = idx / F4, f = idx % F4;
    int gr = rows0 + r;
    float4 val = {0.f, 0.f, 0.f, 0.f};
    if (gr < S.M) val = x4[(size_t)gr * F4 + f];
    f16x4 hv; hv.x = (f16)val.x; hv.y = (f16)val.y; hv.z = (f16)val.z; hv.w = (f16)val.w;
    *reinterpret_cast<f16x4*>(&xs16[r * PP + f * 4]) = hv;
    if constexpr (EPI == 1) {
      if (gr < S.M) {
        float w = S.wnum[gr] * invden_s;
        float4 ov = {val.x * w, val.y * w, val.z * w, val.w * w};
        *reinterpret_cast<float4*>(&S.outx[(size_t)gr * 128 + f * 4]) = ov;
      }
    }
  }
  __syncthreads();
  const int lane = t & 63, w = t >> 6;
  const int m = lane & 15, q = lane >> 4;
  const int rbase = w * 16;
  floatx4 acc[8];
  #pragma unroll
  for (int ct = 0; ct < 8; ++ct) acc[ct] = {0.f, 0.f, 0.f, 0.f};
  const f16x8* Bf8 = reinterpret_cast<const f16x8*>(S.Bf);
  #pragma unroll
  for (int kt = 0; kt < K / 32; ++kt) {
    f16x8 a = *reinterpret_cast<const f16x8*>(&xs16[(rbase + m) * PP + kt * 32 + q * 8]);
    #pragma unroll
    for (int ct = 0; ct < 8; ++ct) {
      f16x8 b = Bf8[(kt * 8 + ct) * 64 + lane];
      acc[ct] = __builtin_amdgcn_mfma_f32_16x16x32_f16(a, b, acc[ct], 0, 0, 0);
    }
  }
  if constexpr (EPI == 0) {
    // ---- hs f16 store: pair columns via xor-1 shuffle
    #pragma unroll
    for (int reg = 0; reg < 4; ++reg) {
      int gr = rows0 + rbase + q * 4 + reg;
      bool ok = gr < S.M;
      #pragma unroll
      for (int cp = 0; cp < 4; ++cp) {
        float v0 = acc[2 * cp][reg], v1 = acc[2 * cp + 1][reg];
        float w0 = __shfl_xor(v0, 1), w1 = __shfl_xor(v1, 1);
        bool even = (m & 1) == 0;
        f16x2 pr;
        pr.x = (f16)(even ? v0 : w1);
        pr.y = (f16)(even ? w0 : v1);
        int col = even ? (2 * cp) * 16 + m : (2 * cp + 1) * 16 + m - 1;
        if (ok) *reinterpret_cast<f16x2*>(&S.hs[(size_t)gr * 128 + col]) = pr;
      }
    }
    // ---- a_s
    float as0[4], as1[4];
    #pragma unroll
    for (int h = 0; h < 4; ++h) { as0[h] = S.asrc[h * 32 + m]; as1[h] = S.asrc[h * 32 + 16 + m]; }
    #pragma unroll
    for (int reg = 0; reg < 4; ++reg) {
      float p[4];
      #pragma unroll
      for (int h = 0; h < 4; ++h)
        p[h] = acc[2 * h][reg] * as0[h] + acc[2 * h + 1][reg] * as1[h];
      #pragma unroll
      for (int off = 1; off < 16; off <<= 1) {
        #pragma unroll
        for (int h = 0; h < 4; ++h) p[h] += __shfl_xor(p[h], off);
      }
      int gr = rows0 + rbase + q * 4 + reg;
      if (m == 0 && gr < S.M) {
        float4 pv = {p[0], p[1], p[2], p[3]};
        *reinterpret_cast<float4*>(&S.asO[gr * 4]) = pv;
      }
    }
    // ---- a_d: GEMV x @ v from LDS
    float qd[4] = {0.f, 0.f, 0.f, 0.f};
    const float4* v4p = reinterpret_cast<const float4*>(S.v);
    constexpr int KS = K / 4;
    #pragma unroll
    for (int i = 0; i < KS; ++i) {
      int k = q * KS + i;
      float xv = (float)xs16[(rbase + m) * PP + k];
      float4 vk = v4p[k];
      qd[0] += xv * vk.x; qd[1] += xv * vk.y; qd[2] += xv * vk.z; qd[3] += xv * vk.w;
    }
    #pragma unroll
    for (int h = 0; h < 4; ++h) {
      qd[h] += __shfl_xor(qd[h], 16);
      qd[h] += __shfl_xor(qd[h], 32);
    }
    int gr2 = rows0 + rbase + m;
    if (q == 0 && gr2 < S.M) {
      float4 qv = {qd[0], qd[1], qd[2], qd[3]};
      *reinterpret_cast<float4*>(&S.adO[gr2 * 4]) = qv;
    }
  } else {
    // ---- fused MLP-2 + heads
    float wn[4];
    #pragma unroll
    for (int reg = 0; reg < 4; ++reg) {
      int gr = rows0 + rbase + q * 4 + reg;
      wn[reg] = (gr < S.M) ? S.wnum[gr] * invden_s : 0.f;
    }
    float bct[8], w2c0[4], w2c1[4], w2rv[4];
    #pragma unroll
    for (int ct = 0; ct < 8; ++ct) bct[ct] = S.bias[ct * 16 + m];
    #pragma unroll
    for (int ct = 0; ct < 4; ++ct) {
      int col = ct * 16 + m;
      w2c0[ct] = S.W2[col * 2];
      w2c1[ct] = S.W2[col * 2 + 1];
      w2rv[ct] = S.w2r[col];
    }
    #pragma unroll
    for (int reg = 0; reg < 4; ++reg) {
      float p0 = 0.f, p1 = 0.f, rr = 0.f;
      #pragma unroll
      for (int ct = 0; ct < 4; ++ct) {
        float hv = fmaxf(acc[ct][reg] * wn[reg] + bct[ct], 0.f);
        p0 += hv * w2c0[ct];
        p1 += hv * w2c1[ct];
      }
      #pragma unroll
      for (int ct = 4; ct < 8; ++ct) {
        float hv = fmaxf(acc[ct][reg] * wn[reg] + bct[ct], 0.f);
        rr += hv * w2rv[ct - 4];
      }
      #pragma unroll
      for (int off = 1; off < 16; off <<= 1) {
        p0 += __shfl_xor(p0, off);
        p1 += __shfl_xor(p1, off);
        rr += __shfl_xor(rr, off);
      }
      int gr = rows0 + rbase + q * 4 + reg;
      if (m == 0 && gr < S.M) {
        float2 pp = {p0 + S.B2[0], p1 + S.B2[1]};
        *reinterpret_cast<float2*>(&S.pred[gr * 2]) = pp;
        float z = rr + S.b2r[0];
        S.risk[gr] = 1.f / (1.f + __expf(-z));
      }
    }
  }
}

// ---------------------------------------------------------------- aggregation
// Two modes, selected per wave:
//  SINGLE (A side, avg deg ~20): one wave per dst, chunks of 16 edges, dual-edge
//    gather (f16x4/lane, 32 lanes per edge), adaptive reductions.
//  PAIR (B side, avg deg ~4): TWO dst per wave, one per 32-lane half.
// Reduction primitives: stride-4/8 levels use DPP row_ror (4-8cy) instead of
// ds_bpermute (~35cy); strides >=16 remain __shfl_xor.
// GLOBAL-MAX FUSION (layer 1): each wave also atomicMax's its attention
// logit's order-preserving key into statsu[slotbase + (blockIdx&15)] — 16
// slots per node type spread contention; k_stats kernel is eliminated.
struct AggSide {
  const int* offs; const int* csr; const float* as_; const float* ad;
  const f16* hs; const float* bias; float* out;
  const float* attw; const float* attb; float* logv;
  unsigned* statsu; int slotbase;
};

__global__ void __launch_bounds__(256) k_agg(AggSide A, AggSide B,
                                             int ndstA, int ndstB, int nwaves) {
  const int wid = (int)blockIdx.x * 4 + ((int)threadIdx.x >> 6);
  if (wid >= nwaves) return;
  const int lane = (int)threadIdx.x & 63;
  if (wid < ndstA) {
    // ------------------------------------------------ SINGLE mode (side A)
    const AggSide S = A;
    const int d = wid;
    const int we = lane >> 2, wh = lane & 3;   // weight role: edge-in-chunk, head
    const int ep = lane >> 5;                  // gather role: edge parity
    const int c4 = lane & 31;                  // gather role: channel quad
    const int gh = c4 >> 3;                    // head of channel quad
    const int c8 = c4 << 3;                    // byte offset of quad in 256B row
    const int wh4 = wh << 2;
    const int beg = __builtin_amdgcn_readfirstlane(S.offs[d]);
    const int end = __builtin_amdgcn_readfirstlane(S.offs[d + 1]);
    const float adv = S.ad[d * 4 + wh];
    const char* __restrict__ hsb = (const char*)S.hs;
    const char* __restrict__ asb = (const char*)S.as_;
    float m_run = -1e30f, den = 0.f;
    float acc0 = 0.f, acc1 = 0.f, acc2 = 0.f, acc3 = 0.f;
    for (int base = beg; base < end; base += 16) {
      const int n = min(16, end - base);
      int sb = 0; float e = -1e30f;
      if (we < n) {
        int s = S.csr[base + we];
        sb = s << 8;
        float asv = *reinterpret_cast<const float*>(asb + (unsigned)((s << 4) + wh4));
        float ev = asv + adv;
        e = (ev > 0.f) ? ev : 0.2f * ev;
      }
      float cm = e;
      cm = fmaxf(cm, dppf<DPP_ROR4>(cm));
      cm = fmaxf(cm, dppf<DPP_ROR8>(cm));
      if (n > 4) cm = fmaxf(cm, __shfl_xor(cm, 16));
      if (n > 8) cm = fmaxf(cm, __shfl_xor(cm, 32));
      const float m_new = fmaxf(m_run, cm);
      const float scale = __expf(m_run - m_new);   // 0 on first chunk
      const float w = __expf(e - m_new);           // 0 for invalid lanes (n>=1 here)
      float ws = w;
      ws += dppf<DPP_ROR4>(ws);
      ws += dppf<DPP_ROR8>(ws);
      if (n > 4) ws += __shfl_xor(ws, 16);
      if (n > 8) ws += __shfl_xor(ws, 32);
      den = den * scale + ws;
      m_run = m_new;
      const float sg = bpermf(scale, gh);
      acc0 *= sg; acc1 *= sg; acc2 *= sg; acc3 *= sg;
      int j = 0;
      for (; j + 8 <= n; j += 8) {     // 8 edges: 4 bperm-s, 4 loads, 4 bperm-w
        int i0 = (j + ep) << 2, i1 = (j + 2 + ep) << 2;
        int i2 = (j + 4 + ep) << 2, i3 = (j + 6 + ep) << 2;
        int s0 = bpermi(sb, i0);
        int s1 = bpermi(sb, i1);
        int s2 = bpermi(sb, i2);
        int s3 = bpermi(sb, i3);
        f16x4 h0 = *reinterpret_cast<const f16x4*>(hsb + (unsigned)(s0 + c8));
        f16x4 h1 = *reinterpret_cast<const f16x4*>(hsb + (unsigned)(s1 + c8));
        f16x4 h2 = *reinterpret_cast<const f16x4*>(hsb + (unsigned)(s2 + c8));
        f16x4 h3 = *reinterpret_cast<const f16x4*>(hsb + (unsigned)(s3 + c8));
        float w0 = bpermf(w, i0 + gh);
        float w1 = bpermf(w, i1 + gh);
        float w2 = bpermf(w, i2 + gh);
        float w3 = bpermf(w, i3 + gh);
        acc0 += w0 * (float)h0.x; acc1 += w0 * (float)h0.y;
        acc2 += w0 * (float)h0.z; acc3 += w0 * (float)h0.w;
        acc0 += w1 * (float)h1.x; acc1 += w1 * (float)h1.y;
        acc2 += w1 * (float)h1.z; acc3 += w1 * (float)h1.w;
        acc0 += w2 * (float)h2.x; acc1 += w2 * (float)h2.y;
        acc2 += w2 * (float)h2.z; acc3 += w2 * (float)h2.w;
        acc0 += w3 * (float)h3.x; acc1 += w3 * (float)h3.y;
        acc2 += w3 * (float)h3.z; acc3 += w3 * (float)h3.w;
      }
      for (; j + 4 <= n; j += 4) {     // 4 edges
        int i0 = (j + ep) << 2, i1 = (j + 2 + ep) << 2;
        int s0 = bpermi(sb, i0);
        int s1 = bpermi(sb, i1);
        f16x4 h0 = *reinterpret_cast<const f16x4*>(hsb + (unsigned)(s0 + c8));
        f16x4 h1 = *reinterpret_cast<const f16x4*>(hsb + (unsigned)(s1 + c8));
        float w0 = bpermf(w, i0 + gh);
        float w1 = bpermf(w, i1 + gh);
        acc0 += w0 * (float)h0.x; acc1 += w0 * (float)h0.y;
        acc2 += w0 * (float)h0.z; acc3 += w0 * (float)h0.w;
        acc0 += w1 * (float)h1.x; acc1 += w1 * (float)h1.y;
        acc2 += w1 * (float)h1.z; acc3 += w1 * (float)h1.w;
      }
      for (; j < n; j += 2) {          // 1-2 edge tail
        int i0 = (j + ep) << 2;
        int s0 = bpermi(sb, i0);
        f16x4 h0 = *reinterpret_cast<const f16x4*>(hsb + (unsigned)(s0 + c8));
        float w0 = bpermf(w, i0 + gh);
        acc0 += w0 * (float)h0.x; acc1 += w0 * (float)h0.y;
        acc2 += w0 * (float)h0.z; acc3 += w0 * (float)h0.w;
      }
    }
    // sum the even-edge and odd-edge halves
    acc0 += __shfl_xor(acc0, 32);
    acc1 += __shfl_xor(acc1, 32);
    acc2 += __shfl_xor(acc2, 32);
    acc3 += __shfl_xor(acc3, 32);
    const float deng = bpermf(den, gh);
    const float invden = (deng > 0.f) ? 1.f / deng : 0.f;
    const float4 b4 = *reinterpret_cast<const float4*>(&S.bias[c4 * 4]);
    float o0 = acc0 * invden + b4.x;
    float o1 = acc1 * invden + b4.y;
    float o2 = acc2 * invden + b4.z;
    float o3 = acc3 * invden + b4.w;
    if (ep == 0) {
      float4 o = {o0, o1, o2, o3};
      *reinterpret_cast<float4*>(&S.out[d * 128 + c4 * 4]) = o;
    }
    if (S.attw) {
      const float4 aw = *reinterpret_cast<const float4*>(&S.attw[c4 * 4]);
      float sl = o0 * aw.x + o1 * aw.y + o2 * aw.z + o3 * aw.w;
      sl += dppf<DPP_XOR1>(sl);
      sl += dppf<DPP_XOR2>(sl);
      sl += dppf<DPP_ROR4>(sl);
      sl += dppf<DPP_ROR8>(sl);
      sl += __shfl_xor(sl, 16);
      float lv = sl + S.attb[0];
      if (lane == 0) {
        S.logv[d] = lv;
        atomicMax(S.statsu + S.slotbase + ((int)blockIdx.x & 15), fkey(lv));
      }
    }
  } else {
    // ------------------------------------------------ PAIR mode (side B)
    const AggSide S = B;
    const int p = wid - ndstA;
    const int half32 = lane & 32;              // bperm base of this half
    const int l5 = lane & 31;
    int d = p * 2 + (lane >> 5);
    const bool dok = d < ndstB;
    if (!dok) d = ndstB - 1;                   // clamp (reads only; writes guarded)
    const int we = l5 >> 2, wh = l5 & 3;       // weight role within half
    const int gh = l5 >> 3;                    // head of channel quad
    const int c8 = l5 << 3;                    // byte offset of quad in 256B row
    const char* __restrict__ hsb = (const char*)S.hs;
    const char* __restrict__ asb = (const char*)S.as_;
    const int beg = S.offs[d];
    const int end = dok ? S.offs[d + 1] : beg; // empty range for clamped dup
    const float adv = S.ad[d * 4 + wh];
    int nch = (end - beg + 7) >> 3;
    int nco = __shfl_xor(nch, 32);
    const int ncmax = __builtin_amdgcn_readfirstlane(max(nch, nco));
    float m_run = -1e30f, den = 0.f;
    float acc0 = 0.f, acc1 = 0.f, acc2 = 0.f, acc3 = 0.f;
    for (int cc = 0; cc < ncmax; ++cc) {
      const int n = min(end - beg - cc * 8, 8);   // may be <=0 for shorter half
      int sb = 0; float e = -1e30f;
      const bool wv = we < n;
      if (wv) {
        int s = S.csr[beg + cc * 8 + we];
        sb = s << 8;
        float asv = *reinterpret_cast<const float*>(asb + (unsigned)((s << 4) + (wh << 2)));
        float ev = asv + adv;
        e = (ev > 0.f) ? ev : 0.2f * ev;
      }
      float cm = e;
      cm = fmaxf(cm, dppf<DPP_ROR4>(cm));
      cm = fmaxf(cm, dppf<DPP_ROR8>(cm));
      cm = fmaxf(cm, __shfl_xor(cm, 16));
      const float m_new = fmaxf(m_run, cm);
      const float scale = __expf(m_run - m_new);        // half-uniform
      const float w = wv ? __expf(e - m_new) : 0.f;     // masked: see header note
      float ws = w;
      ws += dppf<DPP_ROR4>(ws);
      ws += dppf<DPP_ROR8>(ws);
      ws += __shfl_xor(ws, 16);
      den = den * scale + ws;
      m_run = m_new;
      acc0 *= scale; acc1 *= scale; acc2 *= scale; acc3 *= scale;
      int jv = max(n, 0);
      int jo = __shfl_xor(jv, 32);
      const int jm = __builtin_amdgcn_readfirstlane(max(jv, jo));
      int j = 0;
      for (; j + 4 <= jm; j += 4) {
        int i0 = half32 + j * 4, i1 = i0 + 4, i2 = i0 + 8, i3 = i0 + 12;
        int s0 = bpermi(sb, i0);
        int s1 = bpermi(sb, i1);
        int s2 = bpermi(sb, i2);
        int s3 = bpermi(sb, i3);
        f16x4 h0 = *reinterpret_cast<const f16x4*>(hsb + (unsigned)(s0 + c8));
        f16x4 h1 = *reinterpret_cast<const f16x4*>(hsb + (unsigned)(s1 + c8));
        f16x4 h2 = *reinterpret_cast<const f16x4*>(hsb + (unsigned)(s2 + c8));
        f16x4 h3 = *reinterpret_cast<const f16x4*>(hsb + (unsigned)(s3 + c8));
        float w0 = bpermf(w, i0 + gh);
        float w1 = bpermf(w, i1 + gh);
        float w2 = bpermf(w, i2 + gh);
        float w3 = bpermf(w, i3 + gh);
        acc0 += w0 * (float)h0.x; acc1 += w0 * (float)h0.y;
        acc2 += w0 * (float)h0.z; acc3 += w0 * (float)h0.w;
        acc0 += w1 * (float)h1.x; acc1 += w1 * (float)h1.y;
        acc2 += w1 * (float)h1.z; acc3 += w1 * (float)h1.w;
        acc0 += w2 * (float)h2.x; acc1 += w2 * (float)h2.y;
        acc2 += w2 * (float)h2.z; acc3 += w2 * (float)h2.w;
        acc0 += w3 * (float)h3.x; acc1 += w3 * (float)h3.y;
        acc2 += w3 * (float)h3.z; acc3 += w3 * (float)h3.w;
      }
      for (; j < jm; ++j) {
        int i0 = half32 + j * 4;
        int s0 = bpermi(sb, i0);
        f16x4 h0 = *reinterpret_cast<const f16x4*>(hsb + (unsigned)(s0 + c8));
        float w0 = bpermf(w, i0 + gh);
        acc0 += w0 * (float)h0.x; acc1 += w0 * (float)h0.y;
        acc2 += w0 * (float)h0.z; acc3 += w0 * (float)h0.w;
      }
    }
    // den is half-uniform after the reductions
    const float invden = (den > 0.f) ? 1.f / den : 0.f;
    const float4 b4 = *reinterpret_cast<const float4*>(&S.bias[l5 * 4]);
    float o0 = acc0 * invden + b4.x;
    float o1 = acc1 * invden + b4.y;
    float o2 = acc2 * invden + b4.z;
    float o3 = acc3 * invden + b4.w;
    if (dok) {
      float4 o = {o0, o1, o2, o3};
      *reinterpret_cast<float4*>(&S.out[d * 128 + l5 * 4]) = o;
    }
    if (S.attw) {
      const float4 aw = *reinterpret_cast<const float4*>(&S.attw[l5 * 4]);
      float sl = o0 * aw.x + o1 * aw.y + o2 * aw.z + o3 * aw.w;
      sl += dppf<DPP_XOR1>(sl);
      sl += dppf<DPP_XOR2>(sl);
      sl += dppf<DPP_ROR4>(sl);
      sl += dppf<DPP_ROR8>(sl);
      sl += __shfl_xor(sl, 16);
      float lv = sl + S.attb[0];       // half-uniform
      if (l5 == 0 && dok) S.logv[d] = lv;
      // one atomic per wave: lane 0 combines both halves' logits
      float lo = bpermf(lv, 32);
      if (lane == 0)
        atomicMax(S.statsu + S.slotbase + ((int)blockIdx.x & 15),
                  fkey(fmaxf(lv, lo)));
    }
  }
}

// ---------------------------------------------------------------- global softmax
// (max already accumulated into 16 slots/type by k_agg layer 1)
__global__ void __launch_bounds__(256) k_expsum(float* logc, float* logm, float* stats) {
  bool card = (int)blockIdx.x < 256;
  float* logv = card ? logc : logm;
  int n = card ? NC : NM;
  const unsigned* statsu = (const unsigned*)stats;
  int sb0 = card ? 0 : 16;
  float mx = -1e30f;
  #pragma unroll
  for (int i = 0; i < 16; ++i) mx = fmaxf(mx, fdec(statsu[sb0 + i]));
  int b0 = card ? (int)blockIdx.x : (int)blockIdx.x - 256;
  int nb = card ? 256 : 64;
  float local = 0.f;
  for (int i = b0 * 256 + (int)threadIdx.x; i < n; i += nb * 256) {
    float e = __expf(logv[i] - mx);
    logv[i] = e;        // store numerator for later
    local += e;
  }
  __shared__ float sd[256];
  sd[threadIdx.x] = local; __syncthreads();
  for (int off = 128; off > 0; off >>= 1) {
    if ((int)threadIdx.x < off) sd[threadIdx.x] += sd[threadIdx.x + off];
    __syncthreads();
  }
  if (threadIdx.x == 0) atomicAdd(card ? &stats[32] : &stats[33], sd[0]);
}

// ---------------------------------------------------------------- launch
extern "C" void kernel_launch(void* const* d_in, const int* in_sizes, int n_in,
                              void* d_out, int out_size, void* d_ws, size_t ws_size,
                              hipStream_t stream) {
  (void)in_sizes; (void)n_in; (void)out_size; (void)ws_size;
  const float* x_card    = (const float*)d_in[0];
  const float* x_mer     = (const float*)d_in[1];
  const float* l0cm_Wsrc = (const float*)d_in[2];
  const float* l0cm_Wdst = (const float*)d_in[3];
  const float* l0cm_asrc = (const float*)d_in[4];
  const float* l0cm_adst = (const float*)d_in[5];
  const float* l0cm_b    = (const float*)d_in[6];
  const float* l0mc_Wsrc = (const float*)d_in[7];
  const float* l0mc_Wdst = (const float*)d_in[8];
  const float* l0mc_asrc = (const float*)d_in[9];
  const float* l0mc_adst = (const float*)d_in[10];
  const float* l0mc_b    = (const float*)d_in[11];
  const float* l1cm_Wsrc = (const float*)d_in[12];
  const float* l1cm_Wdst = (const float*)d_in[13];
  const float* l1cm_asrc = (const float*)d_in[14];
  const float* l1cm_adst = (const float*)d_in[15];
  const float* l1cm_b    = (const float*)d_in[16];
  const float* l1mc_Wsrc = (const float*)d_in[17];
  const float* l1mc_Wdst = (const float*)d_in[18];
  const float* l1mc_asrc = (const float*)d_in[19];
  const float* l1mc_adst = (const float*)d_in[20];
  const float* l1mc_b    = (const float*)d_in[21];
  const float* attw_c    = (const float*)d_in[22];
  const float* attb_c    = (const float*)d_in[23];
  const float* attw_m    = (const float*)d_in[24];
  const float* attb_m    = (const float*)d_in[25];
  const float* clsc_W1   = (const float*)d_in[26];
  const float* clsc_b1   = (const float*)d_in[27];
  const float* clsc_W2   = (const float*)d_in[28];
  const float* clsc_b2   = (const float*)d_in[29];
  const float* clsm_W1   = (const float*)d_in[30];
  const float* clsm_b1   = (const float*)d_in[31];
  const float* clsm_W2   = (const float*)d_in[32];
  const float* clsm_b2   = (const float*)d_in[33];
  const float* risk_W1   = (const float*)d_in[34];
  const float* risk_b1   = (const float*)d_in[35];
  const float* risk_W2   = (const float*)d_in[36];
  const float* risk_b2   = (const float*)d_in[37];
  const int*   cm_src    = (const int*)d_in[38];
  const int*   cm_dst    = (const int*)d_in[39];
  const int*   mc_src    = (const int*)d_in[40];
  const int*   mc_dst    = (const int*)d_in[41];
  float* out = (float*)d_out;

  float* base = (float*)d_ws;
  size_t o = 0;
  auto alloc = [&](size_t n) { float* p = base + o; o += (n + 3) & ~size_t(3); return p; };
  float* hs_card = alloc((size_t)NC * 128);   // f16 hs for cards (both layers)
  float* xc1     = alloc((size_t)NC * 128);   // xc1, then xc2raw
  float* hs_mer  = alloc((size_t)NM * 128);
  float* xm1     = alloc((size_t)NM * 128);
  float* as_card = alloc((size_t)NC * 4);
  float* ad_card = alloc((size_t)NC * 4);
  float* as_mer  = alloc((size_t)NM * 4);
  float* ad_mer  = alloc((size_t)NM * 4);
  float* v_l0cm  = alloc(512);
  float* v_l0mc  = alloc(512);
  float* v_l1cm  = alloc(512);
  float* v_l1mc  = alloc(512);
  float* bC      = alloc(128);
  float* bM      = alloc(128);
  f16* Bf_l0cm = (f16*)alloc(64 * 128 / 2);
  f16* Bf_l0mc = (f16*)alloc(64 * 128 / 2);
  f16* Bf_l1cm = (f16*)alloc(128 * 128 / 2);
  f16* Bf_l1mc = (f16*)alloc(128 * 128 / 2);
  f16* Bf_catC = (f16*)alloc(128 * 128 / 2);
  f16* Bf_catM = (f16*)alloc(128 * 128 / 2);
  float* logc    = alloc(NC);
  float* logm    = alloc(NM);
  float* stats   = alloc(40);                 // [0..15] ckeys [16..31] mkeys [32..33] dens
  int* cnt_cm  = (int*)alloc(NM);
  int* cnt_mc  = (int*)alloc(NC);
  int* offs_cm = (int*)alloc(NM + 1);
  int* offs_mc = (int*)alloc(NC + 1);
  int* parts   = (int*)alloc(128);
  int* csr_cm  = (int*)alloc(NE);
  int* csr_mc  = (int*)alloc(NE);
  int* rank_cm = (int*)alloc(NE);
  int* rank_mc = (int*)alloc(NE);

  const dim3 B256(256);
  const int gEdge = (NE + 255) / 256;   // 1563 blocks, 1 edge/thread
  // zero histogram counters (cnt_cm and cnt_mc are contiguous in d_ws)
  hipMemsetAsync(cnt_cm, 0, (size_t)(NM + NC) * sizeof(int), stream);
  // fused prep + hist
  k_prep<<<dim3(21 + gEdge), B256, 0, stream>>>(
      (int*)stats,
      l0cm_Wdst, l0cm_adst, v_l0cm, l0mc_Wdst, l0mc_adst, v_l0mc,
      l1cm_Wdst, l1cm_adst, v_l1cm, l1mc_Wdst, l1mc_adst, v_l1mc,
      clsc_b1, clsm_b1, risk_b1, bC, bM,
      l0cm_Wsrc, l0mc_Wsrc, l1cm_Wsrc, l1mc_Wsrc,
      clsc_W1, clsm_W1, risk_W1,
      Bf_l0cm, Bf_l0mc, Bf_l1cm, Bf_l1mc, Bf_catC, Bf_catM,
      cm_dst, mc_dst, cnt_cm, cnt_mc, rank_cm, rank_mc);
  k_scan1<<<dim3(118), B256, 0, stream>>>(cnt_cm, cnt_mc, offs_cm, offs_mc, parts);
  k_scan3<<<dim3(469), B256, 0, stream>>>(offs_cm, offs_mc, parts);

  const int gA = (NC + 63) / 64;   // 1563
  const int gB = (NM + 63) / 64;   // 313
  const int NWAVES = NM + (NC + 1) / 2;   // 20000 single + 50000 pair = 70000
  const int gAgg = (NWAVES + 3) / 4;      // 17500

  GemmSide sA, sB;
  AggSide aA, aB;
  ScatPack sp = {cm_src, cm_dst, mc_src, mc_dst,
                 rank_cm, rank_mc, offs_cm, offs_mc, csr_cm, csr_mc};
  ScatPack spNull = {};
  // ---- layer 0 GEMM fused with CSR scatter (independent work, disjoint pipes)
  sA = {x_card, Bf_l0cm, l0cm_asrc, v_l0mc, (f16*)hs_card, as_card, ad_card,
        nullptr, nullptr, nullptr, nullptr, nullptr, nullptr, nullptr, nullptr,
        nullptr, nullptr, NC};
  sB = {x_mer, Bf_l0mc, l0mc_asrc, v_l0cm, (f16*)hs_mer, as_mer, ad_mer,
        nullptr, nullptr, nullptr, nullptr, nullptr, nullptr, nullptr, nullptr,
        nullptr, nullptr, NM};
  k_gemm<64, 0><<<dim3(gA + gB + gEdge), B256, 0, stream>>>(sA, sB, gA, gA + gB, sp);
  aA = {offs_cm, csr_cm, as_card, ad_mer, (const f16*)hs_card, l0cm_b, xm1,
        nullptr, nullptr, nullptr, nullptr, 0};
  aB = {offs_mc, csr_mc, as_mer, ad_card, (const f16*)hs_mer, l0mc_b, xc1,
        nullptr, nullptr, nullptr, nullptr, 0};
  k_agg<<<dim3(gAgg), B256, 0, stream>>>(aA, aB, NM, NC, NWAVES);
  // ---- layer 1
  sA = {xc1, Bf_l1cm, l1cm_asrc, v_l1mc, (f16*)hs_card, as_card, ad_card,
        nullptr, nullptr, nullptr, nullptr, nullptr, nullptr, nullptr, nullptr,
        nullptr, nullptr, NC};
  sB = {xm1, Bf_l1mc, l1mc_asrc, v_l1cm, (f16*)hs_mer, as_mer, ad_mer,
        nullptr, nullptr, nullptr, nullptr, nullptr, nullptr, nullptr, nullptr,
        nullptr, nullptr, NM};
  k_gemm<128, 0><<<dim3(gA + gB), B256, 0, stream>>>(sA, sB, gA, gA + gB, spNull);
  aA = {offs_cm, csr_cm, as_card, ad_mer, (const f16*)hs_card, l1cm_b, xm1,
        attw_m, attb_m, logm, (unsigned*)stats, 16};
  aB = {offs_mc, csr_mc, as_mer, ad_card, (const f16*)hs_mer, l1mc_b, xc1,
        attw_c, attb_c, logc, (unsigned*)stats, 0};
  k_agg<<<dim3(gAgg), B256, 0, stream>>>(aA, aB, NM, NC, NWAVES);
  // ---- global node softmax (max already fused into agg layer 1)
  k_expsum<<<dim3(320), B256, 0, stream>>>(logc, logm, stats);
  // ---- fused: xc2/xm2 outputs + MLP(hidden+heads) via MFMA
  sA = {xc1, Bf_catC, nullptr, nullptr, nullptr, nullptr, nullptr,
        bC, logc, stats + 32, out,
        clsc_W2, clsc_b2, risk_W2, risk_b2,
        out + OFF_PC, out + OFF_RC, NC};
  sB = {xm1, Bf_catM, nullptr, nullptr, nullptr, nullptr, nullptr,
        bM, logm, stats + 33, out + OFF_XM2,
        clsm_W2, clsm_b2, risk_W2, risk_b2,
        out + OFF_PM, out + OFF_RM, NM};
  k_gemm<128, 1><<<dim3(gA + gB), B256, 0, stream>>>(sA, sB, gA, gA + gB, spNull);
}

// Round 12
// 411.377 us; speedup vs baseline: 2.6480x; 2.6480x over previous
//
#include <hip/hip_runtime.h>

typedef _Float16 f16;
typedef _Float16 f16x2 __attribute__((ext_vector_type(2)));
typedef _Float16 f16x4 __attribute__((ext_vector_type(4)));
typedef _Float16 f16x8 __attribute__((ext_vector_type(8)));
typedef float floatx4 __attribute__((ext_vector_type(4)));

// Problem constants (fixed by the reference)
constexpr int NC = 100000;   // cards
constexpr int NM = 20000;    // merchants
constexpr int NE = 400000;   // edges per edge-type

// d_out layout (floats), concat of (xc2, xm2, pred_c, pred_m, risk_c, risk_m)
constexpr int OFF_XM2 = NC * 128;
constexpr int OFF_PC  = OFF_XM2 + NM * 128;
constexpr int OFF_PM  = OFF_PC + NC * 2;
constexpr int OFF_RC  = OFF_PM + NM * 2;
constexpr int OFF_RM  = OFF_RC + NC;

__device__ __forceinline__ int bpermi(int v, int srclane) {
  return __builtin_amdgcn_ds_bpermute(srclane << 2, v);
}
__device__ __forceinline__ float bpermf(float v, int srclane) {
  int r = __builtin_amdgcn_ds_bpermute(srclane << 2, __builtin_bit_cast(int, v));
  return __builtin_bit_cast(float, r);
}
// DPP cross-lane permute (~4-8cy vs ~35cy for ds_bpermute).
// CTRL: 0x00-0xFF quad_perm; 0x120+N row_ror:N (rotate within 16-lane row).
// Rotations by multiples of 4 preserve head (lane&3) alignment and cover the
// full stride-4 congruence class after ror4+ror8 — equivalent to xor4/xor8
// for max/sum reductions.
template<int CTRL>
__device__ __forceinline__ float dppf(float v) {
  int r = __builtin_amdgcn_update_dpp(0, __builtin_bit_cast(int, v),
                                      CTRL, 0xf, 0xf, true);
  return __builtin_bit_cast(float, r);
}
constexpr int DPP_ROR4  = 0x124;
constexpr int DPP_ROR8  = 0x128;
constexpr int DPP_XOR1  = 0xB1;   // quad_perm [1,0,3,2]
constexpr int DPP_XOR2  = 0x4E;   // quad_perm [2,3,0,1]
// order-preserving float<->uint key (monotonic: a<b <=> fkey(a)<fkey(b))
__device__ __forceinline__ unsigned fkey(float f) {
  unsigned u = __builtin_bit_cast(unsigned, f);
  return (u >> 31) ? ~u : (u | 0x80000000u);
}
__device__ __forceinline__ float fdec(unsigned k) {
  unsigned u = (k >> 31) ? (k ^ 0x80000000u) : ~k;
  return __builtin_bit_cast(float, u);
}

// LESSON (round 10): sustained same-address device-scope atomics (e.g. one
// atomicMax per wave from a hot kernel) serialize through the coherence point
// at ~300ns each — 70K of them cost ~670us. Spread-arrival atomics (one per
// block completion, as in k_stats below) are fine.

// ---------------------------------------------------------------- fused prep + hist
// block 0: a_d GEMV vectors + bias concat + stats init.
// blocks 1..20: swizzle W matrices into MFMA B-fragment fp16 order.
// blocks 21..: edge histogram; the atomicAdd return value IS the edge's rank
// within its dst segment (captured -> scatter becomes atomic-free).
// Counter zeroing is done by hipMemsetAsync BEFORE this kernel (no intra-kernel
// cross-block ordering assumptions).
// B-frag layout (16x16x32): lane holds B[k=kt*32+(lane>>4)*8+j][n=ct*16+(lane&15)],
// flat: dst[((kt*8+ct)*64+lane)*8+j]
__global__ void __launch_bounds__(256) k_prep(
    int* stats_i,
    const float* W0, const float* a0, float* v0,
    const float* W1, const float* a1, float* v1,
    const float* W2, const float* a2, float* v2,
    const float* W3, const float* a3, float* v3,
    const float* cb1, const float* mb1, const float* rb1, float* bC, float* bM,
    const float* S0, const float* S1, const float* S2, const float* S3,
    const float* c1, const float* m1, const float* r1,
    f16* BfL0cm, f16* BfL0mc, f16* BfL1cm, f16* BfL1mc, f16* BfC, f16* BfM,
    const int* cm_dst, const int* mc_dst, int* cnt_cm, int* cnt_mc,
    int* rank_cm, int* rank_mc) {
  int b = blockIdx.x, t = threadIdx.x;
  if (b == 0) {
    const float* Wd[4] = {W0, W1, W2, W3};
    const float* ad[4] = {a0, a1, a2, a3};
    float* vd[4] = {v0, v1, v2, v3};
    for (int idx = t; idx < 1536; idx += 256) {
      int mat, base;
      if (idx < 256)       { mat = 0; base = 0; }
      else if (idx < 512)  { mat = 1; base = 256; }
      else if (idx < 1024) { mat = 2; base = 512; }
      else                 { mat = 3; base = 1024; }
      int local = idx - base, k = local >> 2, h = local & 3;
      const float* W = Wd[mat]; const float* a = ad[mat];
      float s = 0.f;
      for (int c = 0; c < 32; ++c) s += W[k * 128 + h * 32 + c] * a[h * 32 + c];
      vd[mat][local] = s;
    }
    if (t < 128) {
      bC[t] = (t < 64) ? cb1[t] : rb1[t - 64];
      bM[t] = (t < 64) ? mb1[t] : rb1[t - 64];
    }
    if (t < 4) stats_i[t] = 0;   // [maxkey_c, maxkey_m, den_c, den_m]
  } else if (b <= 20) {
    int s = b - 1;
    const float* Wp = nullptr; const float* cA = nullptr; const float* cB = nullptr;
    f16* dst; int kt;
    if (s < 2)       { Wp = S0; dst = BfL0cm; kt = s; }
    else if (s < 4)  { Wp = S1; dst = BfL0mc; kt = s - 2; }
    else if (s < 8)  { Wp = S2; dst = BfL1cm; kt = s - 4; }
    else if (s < 12) { Wp = S3; dst = BfL1mc; kt = s - 8; }
    else if (s < 16) { cA = c1; cB = r1; dst = BfC; kt = s - 12; }
    else             { cA = m1; cB = r1; dst = BfM; kt = s - 16; }
    for (int e = t; e < 512; e += 256) {
      int lane = e & 63, ct = e >> 6;
      int m = lane & 15, q = lane >> 4;
      int col = ct * 16 + m;
      f16x8 frag;
      #pragma unroll
      for (int j = 0; j < 8; ++j) {
        int k = kt * 32 + q * 8 + j;
        float val = Wp ? Wp[k * 128 + col]
                       : (col < 64 ? cA[k * 64 + col] : cB[k * 64 + (col - 64)]);
        frag[j] = (f16)val;
      }
      *reinterpret_cast<f16x8*>(&dst[(size_t)((kt * 8 + ct) * 64 + lane) * 8]) = frag;
    }
  } else {
    int i = (b - 21) * 256 + t;
    if (i < NE) {
      rank_cm[i] = atomicAdd(&cnt_cm[cm_dst[i]], 1);
      rank_mc[i] = atomicAdd(&cnt_mc[mc_dst[i]], 1);
    }
  }
}

__global__ void __launch_bounds__(256) k_scan1(const int* cnt_cm, const int* cnt_mc,
                                               int* offs_cm, int* offs_mc, int* parts) {
  int b = blockIdx.x;
  const int* cnt; int* offs; int n, chunk;
  if (b < 20) { cnt = cnt_cm; offs = offs_cm; n = NM; chunk = b; }
  else        { cnt = cnt_mc; offs = offs_mc; n = NC; chunk = b - 20; }
  int t = threadIdx.x;
  int base = chunk * 1024;
  int v[4]; int tsum = 0;
  #pragma unroll
  for (int j = 0; j < 4; ++j) {
    int idx = base + t * 4 + j;
    v[j] = (idx < n) ? cnt[idx] : 0;
    tsum += v[j];
  }
  __shared__ int sd[256];
  sd[t] = tsum; __syncthreads();
  for (int off = 1; off < 256; off <<= 1) {
    int x = (t >= off) ? sd[t - off] : 0;
    __syncthreads();
    sd[t] += x;
    __syncthreads();
  }
  int excl = sd[t] - tsum;
  int r = excl;
  #pragma unroll
  for (int j = 0; j < 4; ++j) {
    int idx = base + t * 4 + j;
    if (idx < n) offs[idx] = r;
    r += v[j];
  }
  if (t == 0) parts[b] = sd[255];
}

// scan2 merged in: every block redundantly scans the 118 raw partials in LDS
// (parts stays raw -> no cross-block ordering hazard), then applies its slice.
__global__ void __launch_bounds__(256) k_scan3(int* offs_cm, int* offs_mc, const int* parts) {
  __shared__ int sd[128];
  int t = threadIdx.x;
  if (t < 128) sd[t] = (t < 118) ? parts[t] : 0;
  __syncthreads();
  for (int off = 1; off < 128; off <<= 1) {
    int x = 0;
    if (t < 128 && t >= off) x = sd[t - off];
    __syncthreads();
    if (t < 128) sd[t] += x;
    __syncthreads();
  }
  // sd[] now holds the inclusive scan of parts[0..117].
  // cm section = parts[0..19], mc section = parts[20..117]; exclusive within
  // each section: cm p -> sd[p-1]; mc p -> sd[19+p]-sd[19].
  int i = (int)blockIdx.x * 256 + t;
  if (i < NM) {
    int p = i >> 10;
    offs_cm[i] += p ? sd[p - 1] : 0;
  } else if (i < NM + NC) {
    int j = i - NM;
    int p = j >> 10;
    offs_mc[j] += p ? sd[19 + p] - sd[19] : 0;
  }
  if (i == 0) { offs_cm[NM] = NE; offs_mc[NC] = NE; }
}

// ---------------------------------------------------------------- MFMA GEMM
// 64-row x 128-col tile per 256-thread block; 4 waves, each: 16 rows x 128 cols
// via 8 col-tiles of mfma_f32_16x16x32_f16 over K/32 k-tiles.
// C/D layout: col = ct*16 + (lane&15), row = (lane>>4)*4 + reg
// K=64/EPI=0 instantiation additionally carries the atomic-free CSR scatter in
// extra grid blocks (blockIdx >= nGemm): the MFMA-bound gemm and the
// store-bound scatter use disjoint pipes and overlap in one dispatch.
struct GemmSide {
  const float* x; const f16* Bf;
  const float* asrc; const float* v; f16* hs; float* asO; float* adO;   // EPI 0
  const float* bias; const float* wnum; const float* den; float* outx;  // EPI 1
  const float* W2; const float* B2; const float* w2r; const float* b2r;
  float* pred; float* risk;
  int M;
};

struct ScatPack {
  const int* cm_src; const int* cm_dst; const int* mc_src; const int* mc_dst;
  const int* rank_cm; const int* rank_mc; const int* offs_cm; const int* offs_mc;
  int* csr_cm; int* csr_mc;
};

template<int K, int EPI>
__global__ void __launch_bounds__(256) k_gemm(GemmSide A, GemmSide B, int gridA,
                                              int nGemm, ScatPack sp) {
  if constexpr (K == 64 && EPI == 0) {
    if ((int)blockIdx.x >= nGemm) {
      int i = ((int)blockIdx.x - nGemm) * 256 + (int)threadIdx.x;
      if (i < NE) {
        int p = sp.offs_cm[sp.cm_dst[i]] + sp.rank_cm[i];
        sp.csr_cm[p] = sp.cm_src[i];
        int q = sp.offs_mc[sp.mc_dst[i]] + sp.rank_mc[i];
        sp.csr_mc[q] = sp.mc_src[i];
      }
      return;
    }
  }
  constexpr int PP = K + 8;        // fp16 pitch
  constexpr int F4 = K / 4;
  __shared__ f16 xs16[64 * PP];
  const bool isA = (int)blockIdx.x < gridA;
  GemmSide S = isA ? A : B;
  const int blk = isA ? (int)blockIdx.x : (int)blockIdx.x - gridA;
  const int rows0 = blk * 64;
  const int t = (int)threadIdx.x;
  float invden_s = 0.f;
  if constexpr (EPI == 1) invden_s = 1.0f / S.den[0];
  const float4* x4 = reinterpret_cast<const float4*>(S.x);
  #pragma unroll
  for (int ii = 0; ii < (64 * F4) / 256; ++ii) {
    int idx = t + ii * 256;
    int r = idx / F4, f = idx % F4;
    int gr = rows0 + r;
    float4 val = {0.f, 0.f, 0.f, 0.f};
    if (gr < S.M) val = x4[(size_t)gr * F4 + f];
    f16x4 hv; hv.x = (f16)val.x; hv.y = (f16)val.y; hv.z = (f16)val.z; hv.w = (f16)val.w;
    *reinterpret_cast<f16x4*>(&xs16[r * PP + f * 4]) = hv;
    if constexpr (EPI == 1) {
      if (gr < S.M) {
        float w = S.wnum[gr] * invden_s;
        float4 ov = {val.x * w, val.y * w, val.z * w, val.w * w};
        *reinterpret_cast<float4*>(&S.outx[(size_t)gr * 128 + f * 4]) = ov;
      }
    }
  }
  __syncthreads();
  const int lane = t & 63, w = t >> 6;
  const int m = lane & 15, q = lane >> 4;
  const int rbase = w * 16;
  floatx4 acc[8];
  #pragma unroll
  for (int ct = 0; ct < 8; ++ct) acc[ct] = {0.f, 0.f, 0.f, 0.f};
  const f16x8* Bf8 = reinterpret_cast<const f16x8*>(S.Bf);
  #pragma unroll
  for (int kt = 0; kt < K / 32; ++kt) {
    f16x8 a = *reinterpret_cast<const f16x8*>(&xs16[(rbase + m) * PP + kt * 32 + q * 8]);
    #pragma unroll
    for (int ct = 0; ct < 8; ++ct) {
      f16x8 b = Bf8[(kt * 8 + ct) * 64 + lane];
      acc[ct] = __builtin_amdgcn_mfma_f32_16x16x32_f16(a, b, acc[ct], 0, 0, 0);
    }
  }
  if constexpr (EPI == 0) {
    // ---- hs f16 store: pair columns via xor-1 shuffle
    #pragma unroll
    for (int reg = 0; reg < 4; ++reg) {
      int gr = rows0 + rbase + q * 4 + reg;
      bool ok = gr < S.M;
      #pragma unroll
      for (int cp = 0; cp < 4; ++cp) {
        float v0 = acc[2 * cp][reg], v1 = acc[2 * cp + 1][reg];
        float w0 = __shfl_xor(v0, 1), w1 = __shfl_xor(v1, 1);
        bool even = (m & 1) == 0;
        f16x2 pr;
        pr.x = (f16)(even ? v0 : w1);
        pr.y = (f16)(even ? w0 : v1);
        int col = even ? (2 * cp) * 16 + m : (2 * cp + 1) * 16 + m - 1;
        if (ok) *reinterpret_cast<f16x2*>(&S.hs[(size_t)gr * 128 + col]) = pr;
      }
    }
    // ---- a_s
    float as0[4], as1[4];
    #pragma unroll
    for (int h = 0; h < 4; ++h) { as0[h] = S.asrc[h * 32 + m]; as1[h] = S.asrc[h * 32 + 16 + m]; }
    #pragma unroll
    for (int reg = 0; reg < 4; ++reg) {
      float p[4];
      #pragma unroll
      for (int h = 0; h < 4; ++h)
        p[h] = acc[2 * h][reg] * as0[h] + acc[2 * h + 1][reg] * as1[h];
      #pragma unroll
      for (int off = 1; off < 16; off <<= 1) {
        #pragma unroll
        for (int h = 0; h < 4; ++h) p[h] += __shfl_xor(p[h], off);
      }
      int gr = rows0 + rbase + q * 4 + reg;
      if (m == 0 && gr < S.M) {
        float4 pv = {p[0], p[1], p[2], p[3]};
        *reinterpret_cast<float4*>(&S.asO[gr * 4]) = pv;
      }
    }
    // ---- a_d: GEMV x @ v from LDS
    float qd[4] = {0.f, 0.f, 0.f, 0.f};
    const float4* v4p = reinterpret_cast<const float4*>(S.v);
    constexpr int KS = K / 4;
    #pragma unroll
    for (int i = 0; i < KS; ++i) {
      int k = q * KS + i;
      float xv = (float)xs16[(rbase + m) * PP + k];
      float4 vk = v4p[k];
      qd[0] += xv * vk.x; qd[1] += xv * vk.y; qd[2] += xv * vk.z; qd[3] += xv * vk.w;
    }
    #pragma unroll
    for (int h = 0; h < 4; ++h) {
      qd[h] += __shfl_xor(qd[h], 16);
      qd[h] += __shfl_xor(qd[h], 32);
    }
    int gr2 = rows0 + rbase + m;
    if (q == 0 && gr2 < S.M) {
      float4 qv = {qd[0], qd[1], qd[2], qd[3]};
      *reinterpret_cast<float4*>(&S.adO[gr2 * 4]) = qv;
    }
  } else {
    // ---- fused MLP-2 + heads
    float wn[4];
    #pragma unroll
    for (int reg = 0; reg < 4; ++reg) {
      int gr = rows0 + rbase + q * 4 + reg;
      wn[reg] = (gr < S.M) ? S.wnum[gr] * invden_s : 0.f;
    }
    float bct[8], w2c0[4], w2c1[4], w2rv[4];
    #pragma unroll
    for (int ct = 0; ct < 8; ++ct) bct[ct] = S.bias[ct * 16 + m];
    #pragma unroll
    for (int ct = 0; ct < 4; ++ct) {
      int col = ct * 16 + m;
      w2c0[ct] = S.W2[col * 2];
      w2c1[ct] = S.W2[col * 2 + 1];
      w2rv[ct] = S.w2r[col];
    }
    #pragma unroll
    for (int reg = 0; reg < 4; ++reg) {
      float p0 = 0.f, p1 = 0.f, rr = 0.f;
      #pragma unroll
      for (int ct = 0; ct < 4; ++ct) {
        float hv = fmaxf(acc[ct][reg] * wn[reg] + bct[ct], 0.f);
        p0 += hv * w2c0[ct];
        p1 += hv * w2c1[ct];
      }
      #pragma unroll
      for (int ct = 4; ct < 8; ++ct) {
        float hv = fmaxf(acc[ct][reg] * wn[reg] + bct[ct], 0.f);
        rr += hv * w2rv[ct - 4];
      }
      #pragma unroll
      for (int off = 1; off < 16; off <<= 1) {
        p0 += __shfl_xor(p0, off);
        p1 += __shfl_xor(p1, off);
        rr += __shfl_xor(rr, off);
      }
      int gr = rows0 + rbase + q * 4 + reg;
      if (m == 0 && gr < S.M) {
        float2 pp = {p0 + S.B2[0], p1 + S.B2[1]};
        *reinterpret_cast<float2*>(&S.pred[gr * 2]) = pp;
        float z = rr + S.b2r[0];
        S.risk[gr] = 1.f / (1.f + __expf(-z));
      }
    }
  }
}

// ---------------------------------------------------------------- aggregation
// Two modes, selected per wave:
//  SINGLE (A side, avg deg ~20): one wave per dst, chunks of 16 edges, dual-edge
//    gather (f16x4/lane, 32 lanes per edge), adaptive reductions.
//  PAIR (B side, avg deg ~4): TWO dst per wave, one per 32-lane half.
// Reduction primitives: stride-4/8 levels use DPP row_ror (4-8cy) instead of
// ds_bpermute (~35cy); strides >=16 remain __shfl_xor.
struct AggSide {
  const int* offs; const int* csr; const float* as_; const float* ad;
  const f16* hs; const float* bias; float* out;
  const float* attw; const float* attb; float* logv;
};

__global__ void __launch_bounds__(256) k_agg(AggSide A, AggSide B,
                                             int ndstA, int ndstB, int nwaves) {
  const int wid = (int)blockIdx.x * 4 + ((int)threadIdx.x >> 6);
  if (wid >= nwaves) return;
  const int lane = (int)threadIdx.x & 63;
  if (wid < ndstA) {
    // ------------------------------------------------ SINGLE mode (side A)
    const AggSide S = A;
    const int d = wid;
    const int we = lane >> 2, wh = lane & 3;   // weight role: edge-in-chunk, head
    const int ep = lane >> 5;                  // gather role: edge parity
    const int c4 = lane & 31;                  // gather role: channel quad
    const int gh = c4 >> 3;                    // head of channel quad
    const int c8 = c4 << 3;                    // byte offset of quad in 256B row
    const int wh4 = wh << 2;
    const int beg = __builtin_amdgcn_readfirstlane(S.offs[d]);
    const int end = __builtin_amdgcn_readfirstlane(S.offs[d + 1]);
    const float adv = S.ad[d * 4 + wh];
    const char* __restrict__ hsb = (const char*)S.hs;
    const char* __restrict__ asb = (const char*)S.as_;
    float m_run = -1e30f, den = 0.f;
    float acc0 = 0.f, acc1 = 0.f, acc2 = 0.f, acc3 = 0.f;
    for (int base = beg; base < end; base += 16) {
      const int n = min(16, end - base);
      int sb = 0; float e = -1e30f;
      if (we < n) {
        int s = S.csr[base + we];
        sb = s << 8;
        float asv = *reinterpret_cast<const float*>(asb + (unsigned)((s << 4) + wh4));
        float ev = asv + adv;
        e = (ev > 0.f) ? ev : 0.2f * ev;
      }
      float cm = e;
      cm = fmaxf(cm, dppf<DPP_ROR4>(cm));
      cm = fmaxf(cm, dppf<DPP_ROR8>(cm));
      if (n > 4) cm = fmaxf(cm, __shfl_xor(cm, 16));
      if (n > 8) cm = fmaxf(cm, __shfl_xor(cm, 32));
      const float m_new = fmaxf(m_run, cm);
      const float scale = __expf(m_run - m_new);   // 0 on first chunk
      const float w = __expf(e - m_new);           // 0 for invalid lanes (n>=1 here)
      float ws = w;
      ws += dppf<DPP_ROR4>(ws);
      ws += dppf<DPP_ROR8>(ws);
      if (n > 4) ws += __shfl_xor(ws, 16);
      if (n > 8) ws += __shfl_xor(ws, 32);
      den = den * scale + ws;
      m_run = m_new;
      const float sg = bpermf(scale, gh);
      acc0 *= sg; acc1 *= sg; acc2 *= sg; acc3 *= sg;
      int j = 0;
      for (; j + 8 <= n; j += 8) {     // 8 edges: 4 bperm-s, 4 loads, 4 bperm-w
        int i0 = (j + ep) << 2, i1 = (j + 2 + ep) << 2;
        int i2 = (j + 4 + ep) << 2, i3 = (j + 6 + ep) << 2;
        int s0 = bpermi(sb, i0);
        int s1 = bpermi(sb, i1);
        int s2 = bpermi(sb, i2);
        int s3 = bpermi(sb, i3);
        f16x4 h0 = *reinterpret_cast<const f16x4*>(hsb + (unsigned)(s0 + c8));
        f16x4 h1 = *reinterpret_cast<const f16x4*>(hsb + (unsigned)(s1 + c8));
        f16x4 h2 = *reinterpret_cast<const f16x4*>(hsb + (unsigned)(s2 + c8));
        f16x4 h3 = *reinterpret_cast<const f16x4*>(hsb + (unsigned)(s3 + c8));
        float w0 = bpermf(w, i0 + gh);
        float w1 = bpermf(w, i1 + gh);
        float w2 = bpermf(w, i2 + gh);
        float w3 = bpermf(w, i3 + gh);
        acc0 += w0 * (float)h0.x; acc1 += w0 * (float)h0.y;
        acc2 += w0 * (float)h0.z; acc3 += w0 * (float)h0.w;
        acc0 += w1 * (float)h1.x; acc1 += w1 * (float)h1.y;
        acc2 += w1 * (float)h1.z; acc3 += w1 * (float)h1.w;
        acc0 += w2 * (float)h2.x; acc1 += w2 * (float)h2.y;
        acc2 += w2 * (float)h2.z; acc3 += w2 * (float)h2.w;
        acc0 += w3 * (float)h3.x; acc1 += w3 * (float)h3.y;
        acc2 += w3 * (float)h3.z; acc3 += w3 * (float)h3.w;
      }
      for (; j + 4 <= n; j += 4) {     // 4 edges
        int i0 = (j + ep) << 2, i1 = (j + 2 + ep) << 2;
        int s0 = bpermi(sb, i0);
        int s1 = bpermi(sb, i1);
        f16x4 h0 = *reinterpret_cast<const f16x4*>(hsb + (unsigned)(s0 + c8));
        f16x4 h1 = *reinterpret_cast<const f16x4*>(hsb + (unsigned)(s1 + c8));
        float w0 = bpermf(w, i0 + gh);
        float w1 = bpermf(w, i1 + gh);
        acc0 += w0 * (float)h0.x; acc1 += w0 * (float)h0.y;
        acc2 += w0 * (float)h0.z; acc3 += w0 * (float)h0.w;
        acc0 += w1 * (float)h1.x; acc1 += w1 * (float)h1.y;
        acc2 += w1 * (float)h1.z; acc3 += w1 * (float)h1.w;
      }
      for (; j < n; j += 2) {          // 1-2 edge tail
        int i0 = (j + ep) << 2;
        int s0 = bpermi(sb, i0);
        f16x4 h0 = *reinterpret_cast<const f16x4*>(hsb + (unsigned)(s0 + c8));
        float w0 = bpermf(w, i0 + gh);
        acc0 += w0 * (float)h0.x; acc1 += w0 * (float)h0.y;
        acc2 += w0 * (float)h0.z; acc3 += w0 * (float)h0.w;
      }
    }
    // sum the even-edge and odd-edge halves
    acc0 += __shfl_xor(acc0, 32);
    acc1 += __shfl_xor(acc1, 32);
    acc2 += __shfl_xor(acc2, 32);
    acc3 += __shfl_xor(acc3, 32);
    const float deng = bpermf(den, gh);
    const float invden = (deng > 0.f) ? 1.f / deng : 0.f;
    const float4 b4 = *reinterpret_cast<const float4*>(&S.bias[c4 * 4]);
    float o0 = acc0 * invden + b4.x;
    float o1 = acc1 * invden + b4.y;
    float o2 = acc2 * invden + b4.z;
    float o3 = acc3 * invden + b4.w;
    if (ep == 0) {
      float4 o = {o0, o1, o2, o3};
      *reinterpret_cast<float4*>(&S.out[d * 128 + c4 * 4]) = o;
    }
    if (S.attw) {
      const float4 aw = *reinterpret_cast<const float4*>(&S.attw[c4 * 4]);
      float sl = o0 * aw.x + o1 * aw.y + o2 * aw.z + o3 * aw.w;
      sl += dppf<DPP_XOR1>(sl);
      sl += dppf<DPP_XOR2>(sl);
      sl += dppf<DPP_ROR4>(sl);
      sl += dppf<DPP_ROR8>(sl);
      sl += __shfl_xor(sl, 16);
      if (lane == 0) S.logv[d] = sl + S.attb[0];
    }
  } else {
    // ------------------------------------------------ PAIR mode (side B)
    const AggSide S = B;
    const int p = wid - ndstA;
    const int half32 = lane & 32;              // bperm base of this half
    const int l5 = lane & 31;
    int d = p * 2 + (lane >> 5);
    const bool dok = d < ndstB;
    if (!dok) d = ndstB - 1;                   // clamp (reads only; writes guarded)
    const int we = l5 >> 2, wh = l5 & 3;       // weight role within half
    const int gh = l5 >> 3;                    // head of channel quad
    const int c8 = l5 << 3;                    // byte offset of quad in 256B row
    const char* __restrict__ hsb = (const char*)S.hs;
    const char* __restrict__ asb = (const char*)S.as_;
    const int beg = S.offs[d];
    const int end = dok ? S.offs[d + 1] : beg; // empty range for clamped dup
    const float adv = S.ad[d * 4 + wh];
    int nch = (end - beg + 7) >> 3;
    int nco = __shfl_xor(nch, 32);
    const int ncmax = __builtin_amdgcn_readfirstlane(max(nch, nco));
    float m_run = -1e30f, den = 0.f;
    float acc0 = 0.f, acc1 = 0.f, acc2 = 0.f, acc3 = 0.f;
    for (int cc = 0; cc < ncmax; ++cc) {
      const int n = min(end - beg - cc * 8, 8);   // may be <=0 for shorter half
      int sb = 0; float e = -1e30f;
      const bool wv = we < n;
      if (wv) {
        int s = S.csr[beg + cc * 8 + we];
        sb = s << 8;
        float asv = *reinterpret_cast<const float*>(asb + (unsigned)((s << 4) + (wh << 2)));
        float ev = asv + adv;
        e = (ev > 0.f) ? ev : 0.2f * ev;
      }
      float cm = e;
      cm = fmaxf(cm, dppf<DPP_ROR4>(cm));
      cm = fmaxf(cm, dppf<DPP_ROR8>(cm));
      cm = fmaxf(cm, __shfl_xor(cm, 16));
      const float m_new = fmaxf(m_run, cm);
      const float scale = __expf(m_run - m_new);        // half-uniform
      const float w = wv ? __expf(e - m_new) : 0.f;     // masked: see header note
      float ws = w;
      ws += dppf<DPP_ROR4>(ws);
      ws += dppf<DPP_ROR8>(ws);
      ws += __shfl_xor(ws, 16);
      den = den * scale + ws;
      m_run = m_new;
      acc0 *= scale; acc1 *= scale; acc2 *= scale; acc3 *= scale;
      int jv = max(n, 0);
      int jo = __shfl_xor(jv, 32);
      const int jm = __builtin_amdgcn_readfirstlane(max(jv, jo));
      int j = 0;
      for (; j + 4 <= jm; j += 4) {
        int i0 = half32 + j * 4, i1 = i0 + 4, i2 = i0 + 8, i3 = i0 + 12;
        int s0 = bpermi(sb, i0);
        int s1 = bpermi(sb, i1);
        int s2 = bpermi(sb, i2);
        int s3 = bpermi(sb, i3);
        f16x4 h0 = *reinterpret_cast<const f16x4*>(hsb + (unsigned)(s0 + c8));
        f16x4 h1 = *reinterpret_cast<const f16x4*>(hsb + (unsigned)(s1 + c8));
        f16x4 h2 = *reinterpret_cast<const f16x4*>(hsb + (unsigned)(s2 + c8));
        f16x4 h3 = *reinterpret_cast<const f16x4*>(hsb + (unsigned)(s3 + c8));
        float w0 = bpermf(w, i0 + gh);
        float w1 = bpermf(w, i1 + gh);
        float w2 = bpermf(w, i2 + gh);
        float w3 = bpermf(w, i3 + gh);
        acc0 += w0 * (float)h0.x; acc1 += w0 * (float)h0.y;
        acc2 += w0 * (float)h0.z; acc3 += w0 * (float)h0.w;
        acc0 += w1 * (float)h1.x; acc1 += w1 * (float)h1.y;
        acc2 += w1 * (float)h1.z; acc3 += w1 * (float)h1.w;
        acc0 += w2 * (float)h2.x; acc1 += w2 * (float)h2.y;
        acc2 += w2 * (float)h2.z; acc3 += w2 * (float)h2.w;
        acc0 += w3 * (float)h3.x; acc1 += w3 * (float)h3.y;
        acc2 += w3 * (float)h3.z; acc3 += w3 * (float)h3.w;
      }
      for (; j < jm; ++j) {
        int i0 = half32 + j * 4;
        int s0 = bpermi(sb, i0);
        f16x4 h0 = *reinterpret_cast<const f16x4*>(hsb + (unsigned)(s0 + c8));
        float w0 = bpermf(w, i0 + gh);
        acc0 += w0 * (float)h0.x; acc1 += w0 * (float)h0.y;
        acc2 += w0 * (float)h0.z; acc3 += w0 * (float)h0.w;
      }
    }
    // den is half-uniform after the reductions
    const float invden = (den > 0.f) ? 1.f / den : 0.f;
    const float4 b4 = *reinterpret_cast<const float4*>(&S.bias[l5 * 4]);
    float o0 = acc0 * invden + b4.x;
    float o1 = acc1 * invden + b4.y;
    float o2 = acc2 * invden + b4.z;
    float o3 = acc3 * invden + b4.w;
    if (dok) {
      float4 o = {o0, o1, o2, o3};
      *reinterpret_cast<float4*>(&S.out[d * 128 + l5 * 4]) = o;
    }
    if (S.attw) {
      const float4 aw = *reinterpret_cast<const float4*>(&S.attw[l5 * 4]);
      float sl = o0 * aw.x + o1 * aw.y + o2 * aw.z + o3 * aw.w;
      sl += dppf<DPP_XOR1>(sl);
      sl += dppf<DPP_XOR2>(sl);
      sl += dppf<DPP_ROR4>(sl);
      sl += dppf<DPP_ROR8>(sl);
      sl += __shfl_xor(sl, 16);
      if (l5 == 0 && dok) S.logv[d] = sl + S.attb[0];
    }
  }
}

// ---------------------------------------------------------------- global softmax
// 320 blocks (256 card + 64 merchant), per-block partial max, one ordered-uint
// atomicMax per block (320 spread-arrival atomics to 2 addresses — fine;
// see LESSON above re: sustained same-address atomics).
__global__ void __launch_bounds__(256) k_stats(const float* logc, const float* logm,
                                               unsigned* statsu) {
  bool card = (int)blockIdx.x < 256;
  const float* src = card ? logc : logm;
  int n = card ? NC : NM;
  int b0 = card ? (int)blockIdx.x : (int)blockIdx.x - 256;
  int nb = card ? 256 : 64;
  float m = -1e30f;
  for (int i = b0 * 256 + (int)threadIdx.x; i < n; i += nb * 256) m = fmaxf(m, src[i]);
  #pragma unroll
  for (int off = 1; off < 64; off <<= 1) m = fmaxf(m, __shfl_xor(m, off));
  __shared__ float sm[4];
  if (((int)threadIdx.x & 63) == 0) sm[threadIdx.x >> 6] = m;
  __syncthreads();
  if (threadIdx.x == 0) {
    float mm = fmaxf(fmaxf(sm[0], sm[1]), fmaxf(sm[2], sm[3]));
    atomicMax(statsu + (card ? 0 : 1), fkey(mm));
  }
}

__global__ void __launch_bounds__(256) k_expsum(float* logc, float* logm, float* stats) {
  bool card = (int)blockIdx.x < 256;
  float* logv = card ? logc : logm;
  int n = card ? NC : NM;
  const unsigned* statsu = (const unsigned*)stats;
  float mx = fdec(card ? statsu[0] : statsu[1]);
  int b0 = card ? (int)blockIdx.x : (int)blockIdx.x - 256;
  int nb = card ? 256 : 64;
  float local = 0.f;
  for (int i = b0 * 256 + (int)threadIdx.x; i < n; i += nb * 256) {
    float e = __expf(logv[i] - mx);
    logv[i] = e;        // store numerator for later
    local += e;
  }
  __shared__ float sd[256];
  sd[threadIdx.x] = local; __syncthreads();
  for (int off = 128; off > 0; off >>= 1) {
    if ((int)threadIdx.x < off) sd[threadIdx.x] += sd[threadIdx.x + off];
    __syncthreads();
  }
  if (threadIdx.x == 0) atomicAdd(card ? &stats[2] : &stats[3], sd[0]);
}

// ---------------------------------------------------------------- launch
extern "C" void kernel_launch(void* const* d_in, const int* in_sizes, int n_in,
                              void* d_out, int out_size, void* d_ws, size_t ws_size,
                              hipStream_t stream) {
  (void)in_sizes; (void)n_in; (void)out_size; (void)ws_size;
  const float* x_card    = (const float*)d_in[0];
  const float* x_mer     = (const float*)d_in[1];
  const float* l0cm_Wsrc = (const float*)d_in[2];
  const float* l0cm_Wdst = (const float*)d_in[3];
  const float* l0cm_asrc = (const float*)d_in[4];
  const float* l0cm_adst = (const float*)d_in[5];
  const float* l0cm_b    = (const float*)d_in[6];
  const float* l0mc_Wsrc = (const float*)d_in[7];
  const float* l0mc_Wdst = (const float*)d_in[8];
  const float* l0mc_asrc = (const float*)d_in[9];
  const float* l0mc_adst = (const float*)d_in[10];
  const float* l0mc_b    = (const float*)d_in[11];
  const float* l1cm_Wsrc = (const float*)d_in[12];
  const float* l1cm_Wdst = (const float*)d_in[13];
  const float* l1cm_asrc = (const float*)d_in[14];
  const float* l1cm_adst = (const float*)d_in[15];
  const float* l1cm_b    = (const float*)d_in[16];
  const float* l1mc_Wsrc = (const float*)d_in[17];
  const float* l1mc_Wdst = (const float*)d_in[18];
  const float* l1mc_asrc = (const float*)d_in[19];
  const float* l1mc_adst = (const float*)d_in[20];
  const float* l1mc_b    = (const float*)d_in[21];
  const float* attw_c    = (const float*)d_in[22];
  const float* attb_c    = (const float*)d_in[23];
  const float* attw_m    = (const float*)d_in[24];
  const float* attb_m    = (const float*)d_in[25];
  const float* clsc_W1   = (const float*)d_in[26];
  const float* clsc_b1   = (const float*)d_in[27];
  const float* clsc_W2   = (const float*)d_in[28];
  const float* clsc_b2   = (const float*)d_in[29];
  const float* clsm_W1   = (const float*)d_in[30];
  const float* clsm_b1   = (const float*)d_in[31];
  const float* clsm_W2   = (const float*)d_in[32];
  const float* clsm_b2   = (const float*)d_in[33];
  const float* risk_W1   = (const float*)d_in[34];
  const float* risk_b1   = (const float*)d_in[35];
  const float* risk_W2   = (const float*)d_in[36];
  const float* risk_b2   = (const float*)d_in[37];
  const int*   cm_src    = (const int*)d_in[38];
  const int*   cm_dst    = (const int*)d_in[39];
  const int*   mc_src    = (const int*)d_in[40];
  const int*   mc_dst    = (const int*)d_in[41];
  float* out = (float*)d_out;

  float* base = (float*)d_ws;
  size_t o = 0;
  auto alloc = [&](size_t n) { float* p = base + o; o += (n + 3) & ~size_t(3); return p; };
  float* hs_card = alloc((size_t)NC * 128);   // f16 hs for cards (both layers)
  float* xc1     = alloc((size_t)NC * 128);   // xc1, then xc2raw
  float* hs_mer  = alloc((size_t)NM * 128);
  float* xm1     = alloc((size_t)NM * 128);
  float* as_card = alloc((size_t)NC * 4);
  float* ad_card = alloc((size_t)NC * 4);
  float* as_mer  = alloc((size_t)NM * 4);
  float* ad_mer  = alloc((size_t)NM * 4);
  float* v_l0cm  = alloc(512);
  float* v_l0mc  = alloc(512);
  float* v_l1cm  = alloc(512);
  float* v_l1mc  = alloc(512);
  float* bC      = alloc(128);
  float* bM      = alloc(128);
  f16* Bf_l0cm = (f16*)alloc(64 * 128 / 2);
  f16* Bf_l0mc = (f16*)alloc(64 * 128 / 2);
  f16* Bf_l1cm = (f16*)alloc(128 * 128 / 2);
  f16* Bf_l1mc = (f16*)alloc(128 * 128 / 2);
  f16* Bf_catC = (f16*)alloc(128 * 128 / 2);
  f16* Bf_catM = (f16*)alloc(128 * 128 / 2);
  float* logc    = alloc(NC);
  float* logm    = alloc(NM);
  float* stats   = alloc(4);                  // [maxkey_c, maxkey_m, denc, denm]
  int* cnt_cm  = (int*)alloc(NM);
  int* cnt_mc  = (int*)alloc(NC);
  int* offs_cm = (int*)alloc(NM + 1);
  int* offs_mc = (int*)alloc(NC + 1);
  int* parts   = (int*)alloc(128);
  int* csr_cm  = (int*)alloc(NE);
  int* csr_mc  = (int*)alloc(NE);
  int* rank_cm = (int*)alloc(NE);
  int* rank_mc = (int*)alloc(NE);

  const dim3 B256(256);
  const int gEdge = (NE + 255) / 256;   // 1563 blocks, 1 edge/thread
  // zero histogram counters (cnt_cm and cnt_mc are contiguous in d_ws)
  hipMemsetAsync(cnt_cm, 0, (size_t)(NM + NC) * sizeof(int), stream);
  // fused prep + hist
  k_prep<<<dim3(21 + gEdge), B256, 0, stream>>>(
      (int*)stats,
      l0cm_Wdst, l0cm_adst, v_l0cm, l0mc_Wdst, l0mc_adst, v_l0mc,
      l1cm_Wdst, l1cm_adst, v_l1cm, l1mc_Wdst, l1mc_adst, v_l1mc,
      clsc_b1, clsm_b1, risk_b1, bC, bM,
      l0cm_Wsrc, l0mc_Wsrc, l1cm_Wsrc, l1mc_Wsrc,
      clsc_W1, clsm_W1, risk_W1,
      Bf_l0cm, Bf_l0mc, Bf_l1cm, Bf_l1mc, Bf_catC, Bf_catM,
      cm_dst, mc_dst, cnt_cm, cnt_mc, rank_cm, rank_mc);
  k_scan1<<<dim3(118), B256, 0, stream>>>(cnt_cm, cnt_mc, offs_cm, offs_mc, parts);
  k_scan3<<<dim3(469), B256, 0, stream>>>(offs_cm, offs_mc, parts);

  const int gA = (NC + 63) / 64;   // 1563
  const int gB = (NM + 63) / 64;   // 313
  const int NWAVES = NM + (NC + 1) / 2;   // 20000 single + 50000 pair = 70000
  const int gAgg = (NWAVES + 3) / 4;      // 17500

  GemmSide sA, sB;
  AggSide aA, aB;
  ScatPack sp = {cm_src, cm_dst, mc_src, mc_dst,
                 rank_cm, rank_mc, offs_cm, offs_mc, csr_cm, csr_mc};
  ScatPack spNull = {};
  // ---- layer 0 GEMM fused with CSR scatter (independent work, disjoint pipes)
  sA = {x_card, Bf_l0cm, l0cm_asrc, v_l0mc, (f16*)hs_card, as_card, ad_card,
        nullptr, nullptr, nullptr, nullptr, nullptr, nullptr, nullptr, nullptr,
        nullptr, nullptr, NC};
  sB = {x_mer, Bf_l0mc, l0mc_asrc, v_l0cm, (f16*)hs_mer, as_mer, ad_mer,
        nullptr, nullptr, nullptr, nullptr, nullptr, nullptr, nullptr, nullptr,
        nullptr, nullptr, NM};
  k_gemm<64, 0><<<dim3(gA + gB + gEdge), B256, 0, stream>>>(sA, sB, gA, gA + gB, sp);
  aA = {offs_cm, csr_cm, as_card, ad_mer, (const f16*)hs_card, l0cm_b, xm1,
        nullptr, nullptr, nullptr};
  aB = {offs_mc, csr_mc, as_mer, ad_card, (const f16*)hs_mer, l0mc_b, xc1,
        nullptr, nullptr, nullptr};
  k_agg<<<dim3(gAgg), B256, 0, stream>>>(aA, aB, NM, NC, NWAVES);
  // ---- layer 1
  sA = {xc1, Bf_l1cm, l1cm_asrc, v_l1mc, (f16*)hs_card, as_card, ad_card,
        nullptr, nullptr, nullptr, nullptr, nullptr, nullptr, nullptr, nullptr,
        nullptr, nullptr, NC};
  sB = {xm1, Bf_l1mc, l1mc_asrc, v_l1cm, (f16*)hs_mer, as_mer, ad_mer,
        nullptr, nullptr, nullptr, nullptr, nullptr, nullptr, nullptr, nullptr,
        nullptr, nullptr, NM};
  k_gemm<128, 0><<<dim3(gA + gB), B256, 0, stream>>>(sA, sB, gA, gA + gB, spNull);
  aA = {offs_cm, csr_cm, as_card, ad_mer, (const f16*)hs_card, l1cm_b, xm1,
        attw_m, attb_m, logm};
  aB = {offs_mc, csr_mc, as_mer, ad_card, (const f16*)hs_mer, l1mc_b, xc1,
        attw_c, attb_c, logc};
  k_agg<<<dim3(gAgg), B256, 0, stream>>>(aA, aB, NM, NC, NWAVES);
  // ---- global node softmax stats
  k_stats<<<dim3(320), B256, 0, stream>>>(logc, logm, (unsigned*)stats);
  k_expsum<<<dim3(320), B256, 0, stream>>>(logc, logm, stats);
  // ---- fused: xc2/xm2 outputs + MLP(hidden+heads) via MFMA
  sA = {xc1, Bf_catC, nullptr, nullptr, nullptr, nullptr, nullptr,
        bC, logc, stats + 2, out,
        clsc_W2, clsc_b2, risk_W2, risk_b2,
        out + OFF_PC, out + OFF_RC, NC};
  sB = {xm1, Bf_catM, nullptr, nullptr, nullptr, nullptr, nullptr,
        bM, logm, stats + 3, out + OFF_XM2,
        clsm_W2, clsm_b2, risk_W2, risk_b2,
        out + OFF_PM, out + OFF_RM, NM};
  k_gemm<128, 1><<<dim3(gA + gB), B256, 0, stream>>>(sA, sB, gA, gA + gB, spNull);
}